// Round 2
// 135.862 us; speedup vs baseline: 1.0658x; 1.0658x over previous
//
#include <hip/hip_runtime.h>

// Problem constants (from reference setup_inputs)
#define BATCH 256
#define SEQ   2048
#define VOCAB 128000
#define CHUNK 16384              // floats of w_a staged per block (64 KB LDS)
#define CPR   8                  // chunks per row: ceil(128000/16384) = 8

typedef float v4f __attribute__((ext_vector_type(4)));
typedef int   v4i __attribute__((ext_vector_type(4)));
typedef float v2f __attribute__((ext_vector_type(2)));
typedef int   v2i __attribute__((ext_vector_type(2)));

// Grid = BATCH * CPR blocks of 1024 threads. Block (r, c) redundantly computes
// row r's softmax (8 KB re-read; XCD-swizzled so all 8 chunk-blocks of a row
// share one XCD L2 -> row data fetched from HBM once) and owns
// w_a[r, c*CHUNK : c*CHUNK+cnt].
//
// 1024 threads (16 waves), 64 KB LDS -> 2 blocks/CU co-resident (128 KB of
// 160 KB), i.e. 32 waves/CU vs the previous 8: the serial phase chain
// (init -> loads -> reductions -> atomics -> stream) gets 4x the wave-level
// overlap to keep stores in flight.
//
// Dedup without a hash (last-write-wins):
//   LDS chunk as int, init -1.
//   pass1: atomicMax(chunk[tok-base], position_idx)   -- only in-range tokens
//   pass2: holder with chunk[v]==idx writes f32 weight (sign bit 0 => >=0)
//   pass3: stream out; bits<0 means "no token here" -> 0.0f
// Every w_a byte goes to HBM exactly once, coalesced float4.
__global__ __launch_bounds__(1024, 4)
void softmax_scatter_chunked(const float* __restrict__ w_es,
                             const int*   __restrict__ x,
                             float* __restrict__ w_a,     // [BATCH, VOCAB]
                             float* __restrict__ w_out)   // [BATCH, SEQ]
{
    __shared__ int   chunk[CHUNK];
    __shared__ float red[32];      // [0..15] max partials, [16..31] sum partials

    const int bid = blockIdx.x;
    // XCD swizzle: row = bid & 255 -> the 8 chunk-blocks of row r have
    // bid % 8 == r % 8, i.e. land on the same XCD's L2 (round-robin mapping).
    const int r = bid & (BATCH - 1);   // row
    const int c = bid >> 8;            // chunk index within row
    const int base = c * CHUNK;
    const int cnt  = (VOCAB - base < CHUNK) ? (VOCAB - base) : CHUNK; // 16384 or 13312
    const int cnt4 = cnt >> 2;         // 4096 or 3328

    const int t = threadIdx.x;         // 0..1023
    const int lane = t & 63;
    const int wid  = t >> 6;           // 0..15

    // ---- init chunk to -1 (int4): 4 iterations ----
    {
        const v4i m1 = (v4i)(-1);
        #pragma unroll
        for (int j = 0; j < (CHUNK >> 2); j += 1024)
            ((v4i*)chunk)[j + t] = m1;
    }

    // ---- load scores: 2 per thread (float2) ----
    const float* rowp = w_es + (size_t)r * SEQ;
    const v2f a = ((const v2f*)rowp)[t];

    // ---- block max ----
    float m = fmaxf(a.x, a.y);
    #pragma unroll
    for (int off = 32; off > 0; off >>= 1)
        m = fmaxf(m, __shfl_down(m, off, 64));
    if (lane == 0) red[wid] = m;
    __syncthreads();               // also covers chunk init visibility
    m = red[0];
    #pragma unroll
    for (int k = 1; k < 16; ++k) m = fmaxf(m, red[k]);

    // ---- exp + block sum ----
    const float e0 = __expf(a.x - m);
    const float e1 = __expf(a.y - m);
    float s = e0 + e1;
    #pragma unroll
    for (int off = 32; off > 0; off >>= 1)
        s += __shfl_down(s, off, 64);
    if (lane == 0) red[16 + wid] = s;
    __syncthreads();
    s = red[16];
    #pragma unroll
    for (int k = 1; k < 16; ++k) s += red[16 + k];

    const float inv = 1.0f / s;
    const float w0 = e0 * inv;
    const float w1 = e1 * inv;

    // ---- chunk 0's block also writes the weights output ----
    if (c == 0) {
        v2f wv; wv.x = w0; wv.y = w1;
        ((v2f*)(w_out + (size_t)r * SEQ))[t] = wv;
    }

    // ---- load token ids: 2 per thread ----
    const v2i xv = ((const v2i*)(x + (size_t)r * SEQ))[t];
    const int i0 = 2 * t;
    const int i1 = 2 * t + 1;
    const int v0 = xv.x - base;
    const int v1 = xv.y - base;
    const bool in0 = (unsigned)v0 < (unsigned)cnt;
    const bool in1 = (unsigned)v1 < (unsigned)cnt;

    // ---- pass 1: max position index per hit slot ----
    if (in0) atomicMax(&chunk[v0], i0);
    if (in1) atomicMax(&chunk[v1], i1);
    __syncthreads();

    // ---- pass 2: winner writes its weight (f32 bits, sign >= 0) ----
    if (in0 && chunk[v0] == i0) ((float*)chunk)[v0] = w0;
    if (in1 && chunk[v1] == i1) ((float*)chunk)[v1] = w1;
    __syncthreads();

    // ---- pass 3: stream chunk to global; negative bits => empty => 0 ----
    float* gp = w_a + (size_t)r * VOCAB + base;
    #pragma unroll 4
    for (int j = t; j < cnt4; j += 1024) {
        v4i b = ((const v4i*)chunk)[j];
        v4f o;
        o.x = (b.x < 0) ? 0.0f : __int_as_float(b.x);
        o.y = (b.y < 0) ? 0.0f : __int_as_float(b.y);
        o.z = (b.z < 0) ? 0.0f : __int_as_float(b.z);
        o.w = (b.w < 0) ? 0.0f : __int_as_float(b.w);
        ((v4f*)(gp))[j] = o;
    }
}

extern "C" void kernel_launch(void* const* d_in, const int* in_sizes, int n_in,
                              void* d_out, int out_size, void* d_ws, size_t ws_size,
                              hipStream_t stream) {
    const float* w_es = (const float*)d_in[0];
    const int*   x    = (const int*)d_in[1];

    float* out  = (float*)d_out;
    float* w_a  = out;                          // [256, 128000]
    float* w    = out + (size_t)BATCH * VOCAB;  // [256, 2048]

    softmax_scatter_chunked<<<BATCH * CPR, 1024, 0, stream>>>(w_es, x, w_a, w);
}